// Round 2
// baseline (5219.777 us; speedup 1.0000x reference)
//
#include <hip/hip_runtime.h>
#include <hip/hip_bf16.h>
#include <math.h>

// Problem constants (B=4, N=4096, D=1024, 3D=3072)
#define TB 256

// C[M x Nc] = op(A) * B^T (+bias / *alpha with causal mask), all f32 row-major.
// MODE_A 0: A[m][k], rows k-contiguous (transpose-stored into LDS)
// MODE_A 1: A[m][k] = Aptr[k*lda + m] (k-rows m-contiguous, direct-stored)  [used for V^T]
// B is ALWAYS B[n][k] with rows k-contiguous (transpose-stored).
// EPI 0: C = acc + bias[col]            (off unused)
// EPI 1: C = (col > row+off ? -inf : acc*alpha)   [chunked causal S; C rows local]
// EPI 2: C = acc                         (PV)
// KLIMIT: causal k-range limit kend = min(K, n0+off+BN); C cols written at +off.
template<int BM, int BN, int BK, int MODE_A, int EPI, bool KLIMIT>
__global__ __launch_bounds__(TB)
void gemm_f32(const float* __restrict__ A, int lda,
              const float* __restrict__ B, int ldb,
              const float* __restrict__ bias,
              float* __restrict__ C, int ldc,
              int M, int Nc, int K, float alpha, int off)
{
    const int m0 = blockIdx.y * BM;
    const int n0 = blockIdx.x * BN;
    const int tid = threadIdx.x;
    const int tx = tid & 15;   // col group (x4, split 4+4 -> conflict-free b128)
    const int ty = tid >> 4;   // row group

    if (EPI == 1 && n0 > m0 + off + BM - 1) {
        // fully-masked causal block: write -inf, skip compute
        float4 mi; mi.x = mi.y = mi.z = mi.w = -INFINITY;
        #pragma unroll
        for (int i = 0; i < 8; i++) {
            int r = m0 + ((i < 4) ? ty * 4 + i : 64 + ty * 4 + (i - 4));
            *(float4*)&C[(size_t)r * ldc + n0 + tx * 4] = mi;
            *(float4*)&C[(size_t)r * ldc + n0 + 64 + tx * 4] = mi;
        }
        return;
    }

    __shared__ float As[BK][BM];
    __shared__ float Bs[BK][BN];

    float acc[8][8];
    #pragma unroll
    for (int i = 0; i < 8; i++)
        #pragma unroll
        for (int j = 0; j < 8; j++) acc[i][j] = 0.f;

    const int klim = KLIMIT ? (n0 + off + BN) : K;
    const int kend = klim < K ? klim : K;

    for (int k0 = 0; k0 < kend; k0 += BK) {
        // ---- stage A tile (BM x BK) ----
        if (MODE_A == 0) {
            #pragma unroll
            for (int h = 0; h < 2; h++) {
                int f = tid + h * TB;          // 0..511
                int row = f >> 2;              // 0..127
                int kp = (f & 3) * 4;          // 0,4,8,12
                float4 v = *(const float4*)&A[(size_t)(m0 + row) * lda + k0 + kp];
                As[kp + 0][row] = v.x; As[kp + 1][row] = v.y;
                As[kp + 2][row] = v.z; As[kp + 3][row] = v.w;
            }
        } else {
            #pragma unroll
            for (int h = 0; h < 2; h++) {
                int f = tid + h * TB;
                int kk = f >> 5;               // 0..15
                int m4 = (f & 31) * 4;         // 0..124
                *(float4*)&As[kk][m4] = *(const float4*)&A[(size_t)(k0 + kk) * lda + m0 + m4];
            }
        }
        // ---- stage B tile (BN x BK), transpose-store ----
        #pragma unroll
        for (int h = 0; h < 2; h++) {
            int f = tid + h * TB;
            int col = f >> 2;
            int kp = (f & 3) * 4;
            float4 v = *(const float4*)&B[(size_t)(n0 + col) * ldb + k0 + kp];
            Bs[kp + 0][col] = v.x; Bs[kp + 1][col] = v.y;
            Bs[kp + 2][col] = v.z; Bs[kp + 3][col] = v.w;
        }
        __syncthreads();
        #pragma unroll
        for (int kk = 0; kk < BK; kk++) {
            float a[8], b[8];
            *(float4*)&a[0] = *(const float4*)&As[kk][ty * 4];
            *(float4*)&a[4] = *(const float4*)&As[kk][64 + ty * 4];
            *(float4*)&b[0] = *(const float4*)&Bs[kk][tx * 4];
            *(float4*)&b[4] = *(const float4*)&Bs[kk][64 + tx * 4];
            #pragma unroll
            for (int i = 0; i < 8; i++)
                #pragma unroll
                for (int j = 0; j < 8; j++)
                    acc[i][j] = fmaf(a[i], b[j], acc[i][j]);
        }
        __syncthreads();
    }

    // ---- epilogue ----
    #pragma unroll
    for (int i = 0; i < 8; i++) {
        int r = m0 + ((i < 4) ? ty * 4 + i : 64 + ty * 4 + (i - 4));
        #pragma unroll
        for (int g = 0; g < 2; g++) {
            int c = n0 + g * 64 + tx * 4;           // column in GEMM space
            int cw = KLIMIT ? (c + off) : c;        // column in C buffer
            float4 o;
            float* ap = &acc[i][g * 4];
            if (EPI == 0) {
                o.x = ap[0] + bias[c + 0];
                o.y = ap[1] + bias[c + 1];
                o.z = ap[2] + bias[c + 2];
                o.w = ap[3] + bias[c + 3];
            } else if (EPI == 1) {
                int rg = r + off;                   // global causal row
                o.x = (c + 0 > rg) ? -INFINITY : ap[0] * alpha;
                o.y = (c + 1 > rg) ? -INFINITY : ap[1] * alpha;
                o.z = (c + 2 > rg) ? -INFINITY : ap[2] * alpha;
                o.w = (c + 3 > rg) ? -INFINITY : ap[3] * alpha;
            } else {
                o.x = ap[0]; o.y = ap[1]; o.z = ap[2]; o.w = ap[3];
            }
            *(float4*)&C[(size_t)r * ldc + cw] = o;
        }
    }
}

// in-place row softmax, row length 4096, one block (256 thr) per row
__global__ __launch_bounds__(TB)
void softmax_rows4096(float* __restrict__ S)
{
    const int row = blockIdx.x;
    float* p = S + (size_t)row * 4096;
    const int t = threadIdx.x;
    const int wv = t >> 6, ln = t & 63;

    float4 v[4];
    float lm = -INFINITY;
    #pragma unroll
    for (int i = 0; i < 4; i++) {
        v[i] = ((const float4*)p)[t + 256 * i];
        lm = fmaxf(lm, fmaxf(fmaxf(v[i].x, v[i].y), fmaxf(v[i].z, v[i].w)));
    }
    #pragma unroll
    for (int m = 1; m < 64; m <<= 1) lm = fmaxf(lm, __shfl_xor(lm, m, 64));
    __shared__ float redm[4];
    __shared__ float reds[4];
    if (ln == 0) redm[wv] = lm;
    __syncthreads();
    const float mx = fmaxf(fmaxf(redm[0], redm[1]), fmaxf(redm[2], redm[3]));

    float ls = 0.f;
    #pragma unroll
    for (int i = 0; i < 4; i++) {
        v[i].x = __expf(v[i].x - mx);
        v[i].y = __expf(v[i].y - mx);
        v[i].z = __expf(v[i].z - mx);
        v[i].w = __expf(v[i].w - mx);
        ls += v[i].x + v[i].y + v[i].z + v[i].w;
    }
    #pragma unroll
    for (int m = 1; m < 64; m <<= 1) ls += __shfl_xor(ls, m, 64);
    if (ln == 0) reds[wv] = ls;
    __syncthreads();
    const float inv = 1.0f / (reds[0] + reds[1] + reds[2] + reds[3]);
    #pragma unroll
    for (int i = 0; i < 4; i++) {
        v[i].x *= inv; v[i].y *= inv; v[i].z *= inv; v[i].w *= inv;
        ((float4*)p)[t + 256 * i] = v[i];
    }
}

extern "C" void kernel_launch(void* const* d_in, const int* in_sizes, int n_in,
                              void* d_out, int out_size, void* d_ws, size_t ws_size,
                              hipStream_t stream)
{
    const float* x    = (const float*)d_in[0];   // [4,4096,1024]
    const float* Wqkv = (const float*)d_in[1];   // [3072,1024]
    const float* bqkv = (const float*)d_in[2];   // [3072]
    const float* Wo   = (const float*)d_in[3];   // [1024,1024]
    const float* bo   = (const float*)d_in[4];   // [1024]
    float* out = (float*)d_out;                  // [4,4096,1024] f32

    // --- adaptive workspace layout (per-batch pipeline, S chunked) ---
    // qkvb [4096][3072] = 48 MiB, Tb [1024][4096] = 16 MiB, Schunk [CH][4096]
    const size_t fixed = ((size_t)4096 * 3072 + (size_t)1024 * 4096) * sizeof(float);
    int CH = 4096;
    while (CH > 128 && fixed + (size_t)CH * 4096 * sizeof(float) > ws_size) CH >>= 1;

    float* qkvb   = (float*)d_ws;                       // [4096][3072]
    float* Tbuf   = qkvb + (size_t)4096 * 3072;         // [1024][4096] scrambled O_t
    float* Schunk = Tbuf + (size_t)1024 * 4096;         // [CH][4096]

    dim3 blk(TB);

    for (int b = 0; b < 4; b++) {
        const float* xb = x + (size_t)b * 4096 * 1024;
        // 1) qkv_b = x_b @ Wqkv^T + bqkv     [4096 x 3072]
        gemm_f32<128,128,16,0,0,false><<<dim3(24,32),blk,0,stream>>>(
            xb,1024, Wqkv,1024, bqkv, qkvb,3072, 4096,3072,1024, 1.0f, 0);

        const float* Qb = qkvb;
        const float* Kb = qkvb + 1024;
        const float* Vb = qkvb + 2048;

        for (int r0 = 0; r0 < 4096; r0 += CH) {
            // 2) S[r0:r0+CH] = 0.125 * Q[r0:] K^T, causal (-inf), rows stored locally
            gemm_f32<128,128,16,0,1,false><<<dim3(32,CH/128),blk,0,stream>>>(
                Qb + (size_t)r0 * 3072,3072, Kb,3072, nullptr, Schunk,4096,
                CH,4096,1024, 0.125f, r0);
            // 3) softmax rows in place
            softmax_rows4096<<<dim3(CH),blk,0,stream>>>(Schunk);
            // 4) O_t[:, r0:r0+CH] = V^T @ P_chunk^T  (scrambled layout; causal k-limit)
            gemm_f32<128,128,16,1,2,true><<<dim3(CH/128,8),blk,0,stream>>>(
                Vb,3072, Schunk,4096, nullptr, Tbuf,4096,
                1024,CH,4096, 1.0f, r0);
        }

        // 5) out_b = T_b @ Wo^T + bo   (T_b rows = O_t flat rows of 1024)
        gemm_f32<128,128,16,0,0,false><<<dim3(8,32),blk,0,stream>>>(
            Tbuf,1024, Wo,1024, bo, out + (size_t)b * 4096 * 1024,1024,
            4096,1024,1024, 1.0f, 0);
    }
}

// Round 3
// 1098.928 us; speedup vs baseline: 4.7499x; 4.7499x over previous
//
#include <hip/hip_runtime.h>
#include <math.h>

#define TB 256

typedef __attribute__((ext_vector_type(8))) short short8_t;
typedef __attribute__((ext_vector_type(4))) float f32x4;

__device__ __forceinline__ ushort f2bf(float f) {
    uint u = __float_as_uint(f);
    return (ushort)((u + 0x7FFFu + ((u >> 16) & 1u)) >> 16);  // RNE
}

__device__ __forceinline__ void gload_lds16(const void* g, void* l) {
    __builtin_amdgcn_global_load_lds(
        (const __attribute__((address_space(1))) void*)g,
        (__attribute__((address_space(3))) void*)l, 16, 0, 0);
}

// C = A * B^T on bf16 inputs, f32 MFMA accumulate (16x16x32).
// MODE_A 0: A[m][k] bf16 row-major.  MODE_A 1: A=V^T i.e. A[d][n]=V[n][d], V bf16 row-major.
// B[n][k] bf16 row-major always.
// EPI 0: bf16 C = acc + bias[col]
// EPI 1: f32  C = (col > row+off) ? -inf : acc*alpha      (chunk-local rows)
// EPI 2: bf16 C = acc, cols written at +off; kend = min(K, n0+off+BN)
// EPI 3: f32  C = acc + bias[col]
template<int MODE_A, int EPI, bool KLIMIT>
__global__ __launch_bounds__(TB)
void gemm_bf16(const ushort* __restrict__ A, int lda,
               const ushort* __restrict__ B, int ldb,
               const float* __restrict__ bias,
               void* __restrict__ Cv, int ldc,
               int M, int Nc, int K, float alpha, int off)
{
    constexpr int BM = 128, BN = 128, BK = 32;
    const int m0 = blockIdx.y * BM;
    const int n0 = blockIdx.x * BN;
    const int tid = threadIdx.x;
    const int lane = tid & 63;
    const int wid = tid >> 6;
    const int wr = wid >> 1, wc = wid & 1;   // wave -> 64x64 quadrant

    if (EPI == 1 && n0 > m0 + off + BM - 1) {
        // fully-masked causal block: write -inf, skip compute
        float* C = (float*)Cv;
        const int r = tid >> 1, cb = (tid & 1) * 64;
        float4 mi = make_float4(-INFINITY, -INFINITY, -INFINITY, -INFINITY);
        #pragma unroll
        for (int i = 0; i < 16; i++)
            *(float4*)&C[(size_t)(m0 + r) * ldc + n0 + cb + i * 4] = mi;
        return;
    }

    __shared__ __align__(16) ushort As[BM * BK];
    __shared__ __align__(16) ushort Bs[BN * BK];

    f32x4 acc[4][4];
    const f32x4 zero = {0.f, 0.f, 0.f, 0.f};
    #pragma unroll
    for (int mi = 0; mi < 4; mi++)
        #pragma unroll
        for (int ni = 0; ni < 4; ni++) acc[mi][ni] = zero;

    const int klim = KLIMIT ? (n0 + off + BN) : K;
    const int kend = klim < K ? klim : K;

    for (int k0 = 0; k0 < kend; k0 += BK) {
        // ---- stage A tile [BM][BK] ----
        if (MODE_A == 0) {
            #pragma unroll
            for (int h = 0; h < 2; h++) {
                const int c = wid * 2 + h;            // 1KB chunk; dest = base + lane*16
                const int row = c * 16 + (lane >> 2);
                const int kh  = (lane & 3) * 8;
                gload_lds16(&A[(size_t)(m0 + row) * lda + k0 + kh],
                            (char*)As + c * 1024);
            }
        } else {
            // transpose staging: A[d][n] = V[n][d]; read 8 contiguous d, scatter to LDS
            #pragma unroll
            for (int h = 0; h < 2; h++) {
                const int q = tid + h * TB;           // 0..511
                const int kk = q & 31;                // n within tile
                const int db = q >> 5;                // 0..15, d-block of 8
                short8_t gv = *(const short8_t*)&A[(size_t)(k0 + kk) * lda + m0 + db * 8];
                #pragma unroll
                for (int j = 0; j < 8; j++)
                    As[(db * 8 + j) * BK + kk] = (ushort)gv[j];
            }
        }
        // ---- stage B tile [BN][BK] ----
        #pragma unroll
        for (int h = 0; h < 2; h++) {
            const int c = wid * 2 + h;
            const int row = c * 16 + (lane >> 2);
            const int kh  = (lane & 3) * 8;
            gload_lds16(&B[(size_t)(n0 + row) * ldb + k0 + kh],
                        (char*)Bs + c * 1024);
        }
        __syncthreads();   // barrier drains vmcnt/lgkmcnt -> tiles ready

        const int frow = lane & 15;
        const int kh8  = (lane >> 4) * 8;
        short8_t a[4], b[4];
        #pragma unroll
        for (int mi = 0; mi < 4; mi++)
            a[mi] = *(const short8_t*)&As[(wr * 64 + mi * 16 + frow) * BK + kh8];
        #pragma unroll
        for (int ni = 0; ni < 4; ni++)
            b[ni] = *(const short8_t*)&Bs[(wc * 64 + ni * 16 + frow) * BK + kh8];
        #pragma unroll
        for (int mi = 0; mi < 4; mi++)
            #pragma unroll
            for (int ni = 0; ni < 4; ni++)
                acc[mi][ni] = __builtin_amdgcn_mfma_f32_16x16x32_bf16(
                    a[mi], b[ni], acc[mi][ni], 0, 0, 0);
        __syncthreads();   // reads done before next stage overwrites
    }

    // ---- epilogue: D frag col=lane&15, row=(lane>>4)*4+reg ----
    const int col = lane & 15;
    const int rb  = (lane >> 4) * 4;
    #pragma unroll
    for (int mi = 0; mi < 4; mi++) {
        #pragma unroll
        for (int ni = 0; ni < 4; ni++) {
            const int r = m0 + wr * 64 + mi * 16 + rb;
            const int c = n0 + wc * 64 + ni * 16 + col;
            f32x4 v = acc[mi][ni];
            if (EPI == 0) {
                ushort* C = (ushort*)Cv;
                const float bz = bias[c];
                #pragma unroll
                for (int t = 0; t < 4; t++)
                    C[(size_t)(r + t) * ldc + c] = f2bf(v[t] + bz);
            } else if (EPI == 1) {
                float* C = (float*)Cv;
                #pragma unroll
                for (int t = 0; t < 4; t++)
                    C[(size_t)(r + t) * ldc + c] =
                        (c > r + t + off) ? -INFINITY : v[t] * alpha;
            } else if (EPI == 2) {
                ushort* C = (ushort*)Cv;
                #pragma unroll
                for (int t = 0; t < 4; t++)
                    C[(size_t)(r + t) * ldc + c + off] = f2bf(v[t]);
            } else {
                float* C = (float*)Cv;
                const float bz = bias[c];
                #pragma unroll
                for (int t = 0; t < 4; t++)
                    C[(size_t)(r + t) * ldc + c] = v[t] + bz;
            }
        }
    }
}

// f32 -> bf16 cast, vectorized, grid-stride (n4 = n/4)
__global__ __launch_bounds__(TB)
void conv_f32_bf16(const float* __restrict__ in, ushort* __restrict__ out, int n4)
{
    for (int i = blockIdx.x * TB + threadIdx.x; i < n4; i += gridDim.x * TB) {
        float4 v = ((const float4*)in)[i];
        ushort4 o;
        o.x = f2bf(v.x); o.y = f2bf(v.y); o.z = f2bf(v.z); o.w = f2bf(v.w);
        ((ushort4*)out)[i] = o;
    }
}

// row softmax, f32 in -> bf16 out, row length 4096, one 256-thr block per row
__global__ __launch_bounds__(TB)
void softmax_rows4096(const float* __restrict__ S, ushort* __restrict__ P)
{
    const int row = blockIdx.x;
    const float* p = S + (size_t)row * 4096;
    ushort* q = P + (size_t)row * 4096;
    const int t = threadIdx.x;
    const int wv = t >> 6, ln = t & 63;

    float4 v[4];
    float lm = -INFINITY;
    #pragma unroll
    for (int i = 0; i < 4; i++) {
        v[i] = ((const float4*)p)[t + 256 * i];
        lm = fmaxf(lm, fmaxf(fmaxf(v[i].x, v[i].y), fmaxf(v[i].z, v[i].w)));
    }
    #pragma unroll
    for (int m = 1; m < 64; m <<= 1) lm = fmaxf(lm, __shfl_xor(lm, m, 64));
    __shared__ float redm[4];
    __shared__ float reds[4];
    if (ln == 0) redm[wv] = lm;
    __syncthreads();
    const float mx = fmaxf(fmaxf(redm[0], redm[1]), fmaxf(redm[2], redm[3]));

    float ls = 0.f;
    #pragma unroll
    for (int i = 0; i < 4; i++) {
        v[i].x = __expf(v[i].x - mx);
        v[i].y = __expf(v[i].y - mx);
        v[i].z = __expf(v[i].z - mx);
        v[i].w = __expf(v[i].w - mx);
        ls += v[i].x + v[i].y + v[i].z + v[i].w;
    }
    #pragma unroll
    for (int m = 1; m < 64; m <<= 1) ls += __shfl_xor(ls, m, 64);
    if (ln == 0) reds[wv] = ls;
    __syncthreads();
    const float inv = 1.0f / (reds[0] + reds[1] + reds[2] + reds[3]);
    #pragma unroll
    for (int i = 0; i < 4; i++) {
        ushort4 o;
        o.x = f2bf(v[i].x * inv);
        o.y = f2bf(v[i].y * inv);
        o.z = f2bf(v[i].z * inv);
        o.w = f2bf(v[i].w * inv);
        ((ushort4*)q)[t + 256 * i] = o;
    }
}

extern "C" void kernel_launch(void* const* d_in, const int* in_sizes, int n_in,
                              void* d_out, int out_size, void* d_ws, size_t ws_size,
                              hipStream_t stream)
{
    const float* x    = (const float*)d_in[0];   // [4,4096,1024]
    const float* Wqkv = (const float*)d_in[1];   // [3072,1024]
    const float* bqkv = (const float*)d_in[2];   // [3072]
    const float* Wo   = (const float*)d_in[3];   // [1024,1024]
    const float* bo   = (const float*)d_in[4];   // [1024]
    float* out = (float*)d_out;                  // [4,4096,1024] f32

    // ---- workspace layout ----
    ushort* xb   = (ushort*)d_ws;                        // 4*4096*1024   (32 MiB)
    ushort* Wq   = xb  + (size_t)4 * 4096 * 1024;        // 3072*1024     (6 MiB)
    ushort* Wob  = Wq  + (size_t)3072 * 1024;            // 1024*1024     (2 MiB)
    ushort* qkvb = Wob + (size_t)1024 * 1024;            // 4096*3072     (24 MiB)
    ushort* Tb   = qkvb + (size_t)4096 * 3072;           // 4096*1024     (8 MiB)
    ushort* Pch  = Tb  + (size_t)4096 * 1024;            // CH*4096 bf16
    const size_t fixedB = ((size_t)4 * 4096 * 1024 + (size_t)3072 * 1024 +
                           (size_t)1024 * 1024 + (size_t)4096 * 3072 +
                           (size_t)4096 * 1024) * 2;
    int CH = 4096;
    while (CH > 128 && fixedB + (size_t)CH * 4096 * 6 > ws_size) CH >>= 1;
    float* Sch = (float*)(Pch + (size_t)CH * 4096);      // CH*4096 f32

    dim3 blk(TB);

    // input casts (once)
    conv_f32_bf16<<<1024, blk, 0, stream>>>(x,    xb,  4 * 4096 * 1024 / 4);
    conv_f32_bf16<<<256,  blk, 0, stream>>>(Wqkv, Wq,  3072 * 1024 / 4);
    conv_f32_bf16<<<128,  blk, 0, stream>>>(Wo,   Wob, 1024 * 1024 / 4);

    for (int b = 0; b < 4; b++) {
        const ushort* xbb = xb + (size_t)b * 4096 * 1024;
        // 1) qkv_b = x_b @ Wqkv^T + bqkv  -> bf16 [4096][3072]
        gemm_bf16<0, 0, false><<<dim3(24, 32), blk, 0, stream>>>(
            xbb, 1024, Wq, 1024, bqkv, qkvb, 3072, 4096, 3072, 1024, 1.f, 0);

        const ushort* Qb = qkvb;
        const ushort* Kb = qkvb + 1024;
        const ushort* Vb = qkvb + 2048;

        for (int r0 = 0; r0 < 4096; r0 += CH) {
            // 2) S = 0.125 * Q K^T, causal -inf  (f32, chunk rows)
            gemm_bf16<0, 1, false><<<dim3(32, CH / 128), blk, 0, stream>>>(
                Qb + (size_t)r0 * 3072, 3072, Kb, 3072, nullptr,
                Sch, 4096, CH, 4096, 1024, 0.125f, r0);
            // 3) P = softmax(S) -> bf16
            softmax_rows4096<<<dim3(CH), blk, 0, stream>>>(Sch, Pch);
            // 4) O_t[:, r0:r0+CH] = V^T @ P^T  (scrambled layout free; causal k-limit)
            gemm_bf16<1, 2, true><<<dim3(CH / 128, 8), blk, 0, stream>>>(
                Vb, 3072, Pch, 4096, nullptr, Tb, 4096, 1024, CH, 4096, 1.f, r0);
        }

        // 5) out_b = T_b @ Wo^T + bo  (f32)
        gemm_bf16<0, 3, false><<<dim3(8, 32), blk, 0, stream>>>(
            Tb, 1024, Wob, 1024, bo, out + (size_t)b * 4096 * 1024, 1024,
            4096, 1024, 1024, 1.f, 0);
    }
}

// Round 4
// 838.629 us; speedup vs baseline: 6.2242x; 1.3104x over previous
//
#include <hip/hip_runtime.h>
#include <math.h>

#define TB 256

typedef __attribute__((ext_vector_type(8))) short short8_t;
typedef __attribute__((ext_vector_type(4))) float f32x4;

__device__ __forceinline__ ushort f2bf(float f) {
    uint u = __float_as_uint(f);
    return (ushort)((u + 0x7FFFu + ((u >> 16) & 1u)) >> 16);  // RNE
}

__device__ __forceinline__ void gload_lds16(const void* g, void* l) {
    __builtin_amdgcn_global_load_lds(
        (const __attribute__((address_space(1))) void*)g,
        (__attribute__((address_space(3))) void*)l, 16, 0, 0);
}

// C[M x Nc] = A * B^T, bf16 MFMA 16x16x32, f32 accumulate. 128x128x32 tiles,
// double-buffered LDS with issue-early prefetch (T3-minimal 2-phase).
// CONV 1: A is f32, reg-staged + converted. CONV 0: A bf16 via global_load_lds.
// B always bf16 [n][k] row-major via global_load_lds.
// EPI 0: bf16 C = acc + bias[col]      (QKV)
// EPI 1: f32  C = acc * alpha          (S; no mask — softmax masks)
// EPI 2: bf16 C = acc, cols at +off    (PV -> T)
// EPI 3: f32  C = acc + bias[col]      (proj)
// TRI : causal block skip (rows offset by `off`): return if n0 > m0+off+127
// KLIM: kend = min(K, n0+off+BN)       (PV causal k-limit)
template<int CONV, int EPI, bool TRI, bool KLIM>
__global__ __launch_bounds__(TB)
void gemm_bf16(const void* __restrict__ Av, int lda,
               const ushort* __restrict__ B, int ldb,
               const float* __restrict__ bias,
               void* __restrict__ Cv, int ldc,
               int M, int Nc, int K, float alpha, int off)
{
    constexpr int BM = 128, BN = 128, BK = 32;
    const int m0 = blockIdx.y * BM;
    const int n0 = blockIdx.x * BN;
    if (TRI && n0 > m0 + off + BM - 1) return;   // fully-masked causal block

    const int tid = threadIdx.x;
    const int lane = tid & 63;
    const int wid = tid >> 6;
    const int wr = wid >> 1, wc = wid & 1;       // wave -> 64x64 quadrant

    __shared__ __align__(16) ushort As[2][BM * BK];
    __shared__ __align__(16) ushort Bs[2][BN * BK];

    f32x4 acc[4][4];
    const f32x4 zero = {0.f, 0.f, 0.f, 0.f};
    #pragma unroll
    for (int mi = 0; mi < 4; mi++)
        #pragma unroll
        for (int ni = 0; ni < 4; ni++) acc[mi][ni] = zero;

    const int klim = KLIM ? (n0 + off + BN) : K;
    const int kend = klim < K ? klim : K;
    const int nt = kend / BK;

    auto STAGE = [&](int t, int bufi) {
        const int k0 = t * BK;
        if (CONV) {
            const float* Af = (const float*)Av;
            #pragma unroll
            for (int h = 0; h < 2; h++) {
                const int q = tid + h * TB;      // 0..511
                const int row = q >> 2;          // 0..127
                const int kp = (q & 3) * 8;      // 0,8,16,24
                const float* src = &Af[(size_t)(m0 + row) * lda + k0 + kp];
                float4 u0 = *(const float4*)src;
                float4 u1 = *(const float4*)(src + 4);
                short8_t s;
                s[0] = (short)f2bf(u0.x); s[1] = (short)f2bf(u0.y);
                s[2] = (short)f2bf(u0.z); s[3] = (short)f2bf(u0.w);
                s[4] = (short)f2bf(u1.x); s[5] = (short)f2bf(u1.y);
                s[6] = (short)f2bf(u1.z); s[7] = (short)f2bf(u1.w);
                *(short8_t*)&As[bufi][row * BK + kp] = s;
            }
        } else {
            const ushort* Ab = (const ushort*)Av;
            #pragma unroll
            for (int h = 0; h < 2; h++) {
                const int c = wid * 2 + h;       // 1KB chunk; dest = base + lane*16
                const int row = c * 16 + (lane >> 2);
                const int kh  = (lane & 3) * 8;
                gload_lds16(&Ab[(size_t)(m0 + row) * lda + k0 + kh],
                            (char*)&As[bufi][0] + c * 1024);
            }
        }
        #pragma unroll
        for (int h = 0; h < 2; h++) {
            const int c = wid * 2 + h;
            const int row = c * 16 + (lane >> 2);
            const int kh  = (lane & 3) * 8;
            gload_lds16(&B[(size_t)(n0 + row) * ldb + k0 + kh],
                        (char*)&Bs[bufi][0] + c * 1024);
        }
    };

    STAGE(0, 0);
    __syncthreads();                 // tile 0 ready

    for (int t = 0; t < nt; t++) {
        const int cur = t & 1;
        if (t + 1 < nt) STAGE(t + 1, cur ^ 1);   // issue-early: hides under MFMA

        const int frow = lane & 15;
        const int kh8  = (lane >> 4) * 8;
        short8_t a[4], b[4];
        #pragma unroll
        for (int mi = 0; mi < 4; mi++)
            a[mi] = *(const short8_t*)&As[cur][(wr * 64 + mi * 16 + frow) * BK + kh8];
        #pragma unroll
        for (int ni = 0; ni < 4; ni++)
            b[ni] = *(const short8_t*)&Bs[cur][(wc * 64 + ni * 16 + frow) * BK + kh8];
        #pragma unroll
        for (int mi = 0; mi < 4; mi++)
            #pragma unroll
            for (int ni = 0; ni < 4; ni++)
                acc[mi][ni] = __builtin_amdgcn_mfma_f32_16x16x32_bf16(
                    a[mi], b[ni], acc[mi][ni], 0, 0, 0);
        __syncthreads();   // drains vmcnt(0): next tile ready; reads done before overwrite
    }

    // ---- epilogue: D frag col=lane&15, row=(lane>>4)*4+reg ----
    const int col = lane & 15;
    const int rb  = (lane >> 4) * 4;
    #pragma unroll
    for (int mi = 0; mi < 4; mi++) {
        #pragma unroll
        for (int ni = 0; ni < 4; ni++) {
            const int r = m0 + wr * 64 + mi * 16 + rb;
            const int c = n0 + wc * 64 + ni * 16 + col;
            f32x4 v = acc[mi][ni];
            if (EPI == 0) {
                ushort* C = (ushort*)Cv;
                const float bz = bias[c];
                #pragma unroll
                for (int t = 0; t < 4; t++)
                    C[(size_t)(r + t) * ldc + c] = f2bf(v[t] + bz);
            } else if (EPI == 1) {
                float* C = (float*)Cv;
                #pragma unroll
                for (int t = 0; t < 4; t++)
                    C[(size_t)(r + t) * ldc + c] = v[t] * alpha;
            } else if (EPI == 2) {
                ushort* C = (ushort*)Cv;
                #pragma unroll
                for (int t = 0; t < 4; t++)
                    C[(size_t)(r + t) * ldc + c + off] = f2bf(v[t]);
            } else {
                float* C = (float*)Cv;
                const float bz = bias[c];
                #pragma unroll
                for (int t = 0; t < 4; t++)
                    C[(size_t)(r + t) * ldc + c] = v[t] + bz;
            }
        }
    }
}

// f32 -> bf16 cast (weights only), n4 = n/4
__global__ __launch_bounds__(TB)
void conv_f32_bf16(const float* __restrict__ in, ushort* __restrict__ out, int n4)
{
    for (int i = blockIdx.x * TB + threadIdx.x; i < n4; i += gridDim.x * TB) {
        float4 v = ((const float4*)in)[i];
        ushort4 o;
        o.x = f2bf(v.x); o.y = f2bf(v.y); o.z = f2bf(v.z); o.w = f2bf(v.w);
        ((ushort4*)out)[i] = o;
    }
}

// V [4096][1024] (row stride ldv) -> Vt [1024][4096], bf16, 64x64 LDS tiles
__global__ __launch_bounds__(TB)
void transposeV(const ushort* __restrict__ V, int ldv, ushort* __restrict__ Vt)
{
    __shared__ ushort Ls[64][65];
    const int n0 = blockIdx.x * 64, d0 = blockIdx.y * 64;
    const int t = threadIdx.x;
    #pragma unroll
    for (int p = 0; p < 4; p++) {
        const int row = p * 16 + (t >> 4);
        const int c4 = (t & 15) * 4;
        ushort4 v = *(const ushort4*)&V[(size_t)(n0 + row) * ldv + d0 + c4];
        Ls[row][c4 + 0] = v.x; Ls[row][c4 + 1] = v.y;
        Ls[row][c4 + 2] = v.z; Ls[row][c4 + 3] = v.w;
    }
    __syncthreads();
    #pragma unroll
    for (int p = 0; p < 4; p++) {
        const int d = p * 16 + (t >> 4);
        const int n4 = (t & 15) * 4;
        ushort4 o;
        o.x = Ls[n4 + 0][d]; o.y = Ls[n4 + 1][d];
        o.z = Ls[n4 + 2][d]; o.w = Ls[n4 + 3][d];
        *(ushort4*)&Vt[(size_t)(d0 + d) * 4096 + n0 + n4] = o;
    }
}

// prefix-causal row softmax: row r = r0+blockIdx.x, compute over [0,r],
// write bf16 P over [0, pe) with zeros in (r, pe), pe = 128-aligned end.
__global__ __launch_bounds__(TB)
void softmax_prefix(float* __restrict__ S, ushort* __restrict__ P, int r0)
{
    const int local = blockIdx.x;
    const int r = r0 + local;
    const int pe = ((r >> 7) << 7) + 128;
    float* p = S + (size_t)local * 4096;
    ushort* q = P + (size_t)local * 4096;
    const int t = threadIdx.x;
    const int wv = t >> 6, ln = t & 63;
    __shared__ float red[4];

    float lm = -INFINITY;
    for (int k4 = t * 4; k4 < pe; k4 += 1024) {
        float4 v = *(const float4*)&p[k4];
        lm = (k4 + 0 <= r) ? fmaxf(lm, v.x) : lm;
        lm = (k4 + 1 <= r) ? fmaxf(lm, v.y) : lm;
        lm = (k4 + 2 <= r) ? fmaxf(lm, v.z) : lm;
        lm = (k4 + 3 <= r) ? fmaxf(lm, v.w) : lm;
    }
    #pragma unroll
    for (int m = 1; m < 64; m <<= 1) lm = fmaxf(lm, __shfl_xor(lm, m, 64));
    if (ln == 0) red[wv] = lm;
    __syncthreads();
    const float mx = fmaxf(fmaxf(red[0], red[1]), fmaxf(red[2], red[3]));
    __syncthreads();

    float ls = 0.f;
    for (int k4 = t * 4; k4 < pe; k4 += 1024) {
        float4 v = *(const float4*)&p[k4];
        float4 e;
        e.x = (k4 + 0 <= r) ? __expf(v.x - mx) : 0.f;
        e.y = (k4 + 1 <= r) ? __expf(v.y - mx) : 0.f;
        e.z = (k4 + 2 <= r) ? __expf(v.z - mx) : 0.f;
        e.w = (k4 + 3 <= r) ? __expf(v.w - mx) : 0.f;
        ls += e.x + e.y + e.z + e.w;
        *(float4*)&p[k4] = e;
    }
    #pragma unroll
    for (int m = 1; m < 64; m <<= 1) ls += __shfl_xor(ls, m, 64);
    if (ln == 0) red[wv] = ls;
    __syncthreads();
    const float inv = 1.0f / (red[0] + red[1] + red[2] + red[3]);
    for (int k4 = t * 4; k4 < pe; k4 += 1024) {
        float4 e = *(const float4*)&p[k4];
        ushort4 o;
        o.x = f2bf(e.x * inv); o.y = f2bf(e.y * inv);
        o.z = f2bf(e.z * inv); o.w = f2bf(e.w * inv);
        *(ushort4*)&q[k4] = o;
    }
}

extern "C" void kernel_launch(void* const* d_in, const int* in_sizes, int n_in,
                              void* d_out, int out_size, void* d_ws, size_t ws_size,
                              hipStream_t stream)
{
    const float* x    = (const float*)d_in[0];   // [4,4096,1024]
    const float* Wqkv = (const float*)d_in[1];   // [3072,1024]
    const float* bqkv = (const float*)d_in[2];   // [3072]
    const float* Wo   = (const float*)d_in[3];   // [1024,1024]
    const float* bo   = (const float*)d_in[4];   // [1024]
    float* out = (float*)d_out;                  // [4,4096,1024] f32

    // ---- workspace (bf16 units unless noted) ----
    ushort* Wq   = (ushort*)d_ws;                       // 3072*1024   (6 MiB)
    ushort* Wob  = Wq   + (size_t)3072 * 1024;          // 1024*1024   (2 MiB)
    ushort* qkvb = Wob  + (size_t)1024 * 1024;          // 4096*3072   (24 MiB)
    ushort* Vtb  = qkvb + (size_t)4096 * 3072;          // 1024*4096   (8 MiB)
    ushort* Tall = Vtb  + (size_t)1024 * 4096;          // 4*4096*1024 (32 MiB)
    ushort* Pch  = Tall + (size_t)4 * 4096 * 1024;      // CH*4096 bf16
    const size_t fixedB = ((size_t)3072 * 1024 + (size_t)1024 * 1024 +
                           (size_t)4096 * 3072 + (size_t)1024 * 4096 +
                           (size_t)4 * 4096 * 1024) * 2;
    int CH = 4096;
    while (CH > 512 && fixedB + (size_t)CH * 4096 * 6 > ws_size) CH >>= 1;
    float* Sch = (float*)(Pch + (size_t)CH * 4096);     // CH*4096 f32

    dim3 blk(TB);

    conv_f32_bf16<<<256, blk, 0, stream>>>(Wqkv, Wq,  3072 * 1024 / 4);
    conv_f32_bf16<<<128, blk, 0, stream>>>(Wo,   Wob, 1024 * 1024 / 4);

    for (int b = 0; b < 4; b++) {
        const float* xb = x + (size_t)b * 4096 * 1024;
        // 1) qkv_b = x_b @ Wqkv^T + bqkv  (f32 A converted in-staging)
        gemm_bf16<1, 0, false, false><<<dim3(24, 32), blk, 0, stream>>>(
            xb, 1024, Wq, 1024, bqkv, qkvb, 3072, 4096, 3072, 1024, 1.f, 0);

        // V -> Vt once per batch
        transposeV<<<dim3(64, 16), blk, 0, stream>>>(qkvb + 2048, 3072, Vtb);

        const ushort* Qb = qkvb;
        const ushort* Kb = qkvb + 1024;

        for (int r0 = 0; r0 < 4096; r0 += CH) {
            // 2) S = 0.125 * Q K^T (triangular blocks only; unmasked values)
            gemm_bf16<0, 1, true, false><<<dim3(32, CH / 128), blk, 0, stream>>>(
                Qb + (size_t)r0 * 3072, 3072, Kb, 3072, nullptr,
                Sch, 4096, CH, 4096, 1024, 0.125f, r0);
            // 3) P = prefix-softmax(S) -> bf16 (zero-padded to 128-boundary)
            softmax_prefix<<<dim3(CH), blk, 0, stream>>>(Sch, Pch, r0);
            // 4) O_t[:, r0:r0+CH] = Vt @ P^T  (scrambled layout free; causal k-limit)
            gemm_bf16<0, 2, false, true><<<dim3(CH / 128, 8), blk, 0, stream>>>(
                Vtb, 4096, Pch, 4096, nullptr,
                Tall + (size_t)b * 4096 * 1024, 4096, 1024, CH, 4096, 1.f, r0);
        }
    }

    // 5) out = T @ Wo^T + bo  (all batches, one GEMM)
    gemm_bf16<0, 3, false, false><<<dim3(8, 128), blk, 0, stream>>>(
        Tall, 1024, Wob, 1024, bo, out, 1024, 16384, 1024, 1024, 1.f, 0);
}